// Round 2
// baseline (425.656 us; speedup 1.0000x reference)
//
#include <hip/hip_runtime.h>
#include <math.h>

#define NSEG 129
#define NGROUP 128
#define NIMG 4
#define R 4            // LDS histogram replicas (indexed by lane & 3)

// ALPHA=10, BETA=2 ; C = ALPHA - ALPHA*ln(1+ALPHA/BETA) = 10 - 10*ln(6)
#define WING_C (-7.917594692280550f)

// ---------------------------------------------------------------------------
// Pass 1: per-(img,seg) counts and sums via replicated per-block LDS histogram.
// grid = (blocksX, NIMG), block = 256
__global__ __launch_bounds__(256) void accum_kernel(const float4* __restrict__ pred,
                                                    const int* __restrict__ gt,
                                                    float* __restrict__ counts,
                                                    float* __restrict__ sums,
                                                    int n) {
    // layout: s_cnt[seg*R + r]; s_sum[k*NSEG*R + seg*R + r]
    // bank(s_sum) = (4k + 4seg + r) % 32 -> 32 banks covered per instr.
    __shared__ float s_cnt[NSEG * R];
    __shared__ float s_sum[4 * NSEG * R];
    const int img = blockIdx.y;
    for (int i = threadIdx.x; i < NSEG * R; i += 256) s_cnt[i] = 0.f;
    for (int i = threadIdx.x; i < 4 * NSEG * R; i += 256) s_sum[i] = 0.f;
    __syncthreads();

    const int r = threadIdx.x & (R - 1);
    const float4* p = pred + (size_t)img * n;
    const int* g = gt + (size_t)img * n;
    for (int i = blockIdx.x * 256 + threadIdx.x; i < n; i += gridDim.x * 256) {
        int seg = g[i] + 1;
        seg = max(0, min(NSEG - 1, seg));
        float4 v = p[i];
        int base = seg * R + r;
        atomicAdd(&s_cnt[base], 1.f);
        atomicAdd(&s_sum[0 * NSEG * R + base], v.x);
        atomicAdd(&s_sum[1 * NSEG * R + base], v.y);
        atomicAdd(&s_sum[2 * NSEG * R + base], v.z);
        atomicAdd(&s_sum[3 * NSEG * R + base], v.w);
    }
    __syncthreads();

    for (int i = threadIdx.x; i < NSEG; i += 256) {
        float c = s_cnt[i * R + 0] + s_cnt[i * R + 1] + s_cnt[i * R + 2] + s_cnt[i * R + 3];
        if (c != 0.f) {
            atomicAdd(&counts[img * NSEG + i], c);
            #pragma unroll
            for (int k = 0; k < 4; ++k) {
                const float* b = &s_sum[k * NSEG * R + i * R];
                atomicAdd(&sums[(img * NSEG + i) * 4 + k], b[0] + b[1] + b[2] + b[3]);
            }
        }
    }
}

// ---------------------------------------------------------------------------
// Pass 2: means = sums / max(counts, 1)
__global__ __launch_bounds__(256) void means_kernel(const float* __restrict__ counts,
                                                    const float* __restrict__ sums,
                                                    float* __restrict__ means) {
    int idx = blockIdx.x * 256 + threadIdx.x;  // over NIMG*NSEG
    if (idx < NIMG * NSEG) {
        float c = fmaxf(counts[idx], 1.f);
        means[idx * 4 + 0] = sums[idx * 4 + 0] / c;
        means[idx * 4 + 1] = sums[idx * 4 + 1] / c;
        means[idx * 4 + 2] = sums[idx * 4 + 2] / c;
        means[idx * 4 + 3] = sums[idx * 4 + 3] / c;
    }
}

// ---------------------------------------------------------------------------
// Pass 3: wing loss per element against means[seg]; segment-sum via replicated LDS.
__global__ __launch_bounds__(256) void wl_kernel(const float4* __restrict__ pred,
                                                 const int* __restrict__ gt,
                                                 const float* __restrict__ means,
                                                 float* __restrict__ wlsum,
                                                 int n) {
    __shared__ float s_mean[NSEG * 5];   // stride 5: bank = (5*seg+k)%32, coprime -> spread
    __shared__ float s_wl[NSEG * R];
    const int img = blockIdx.y;
    for (int i = threadIdx.x; i < NSEG; i += 256) {
        s_mean[i * 5 + 0] = means[(img * NSEG + i) * 4 + 0];
        s_mean[i * 5 + 1] = means[(img * NSEG + i) * 4 + 1];
        s_mean[i * 5 + 2] = means[(img * NSEG + i) * 4 + 2];
        s_mean[i * 5 + 3] = means[(img * NSEG + i) * 4 + 3];
    }
    for (int i = threadIdx.x; i < NSEG * R; i += 256) s_wl[i] = 0.f;
    __syncthreads();

    const int r = threadIdx.x & (R - 1);
    const float4* p = pred + (size_t)img * n;
    const int* g = gt + (size_t)img * n;
    for (int i = blockIdx.x * 256 + threadIdx.x; i < n; i += gridDim.x * 256) {
        int seg = g[i] + 1;
        seg = max(0, min(NSEG - 1, seg));
        float4 v = p[i];
        float d0 = fabsf(v.x - s_mean[seg * 5 + 0]);
        float d1 = fabsf(v.y - s_mean[seg * 5 + 1]);
        float d2 = fabsf(v.z - s_mean[seg * 5 + 2]);
        float d3 = fabsf(v.w - s_mean[seg * 5 + 3]);
        float w = 0.f;
        w += (d0 < 10.f) ? 10.f * log1pf(d0 * 0.5f) : (d0 - WING_C);
        w += (d1 < 10.f) ? 10.f * log1pf(d1 * 0.5f) : (d1 - WING_C);
        w += (d2 < 10.f) ? 10.f * log1pf(d2 * 0.5f) : (d2 - WING_C);
        w += (d3 < 10.f) ? 10.f * log1pf(d3 * 0.5f) : (d3 - WING_C);
        atomicAdd(&s_wl[seg * R + r], w);
    }
    __syncthreads();

    for (int i = threadIdx.x; i < NSEG; i += 256) {
        float w = s_wl[i * R + 0] + s_wl[i * R + 1] + s_wl[i * R + 2] + s_wl[i * R + 3];
        if (w != 0.f) atomicAdd(&wlsum[img * NSEG + i], w);
    }
}

// ---------------------------------------------------------------------------
// Pass 4: per-image pull + push, averaged. Single block.
__global__ __launch_bounds__(256) void final_kernel(const float* __restrict__ counts,
                                                    const float* __restrict__ wlsum,
                                                    const float* __restrict__ means,
                                                    float* __restrict__ out) {
    __shared__ float s_tag[NGROUP * 4];
    __shared__ float s_valid[NGROUP];
    __shared__ float s_num, s_pull, s_push, s_total;
    const int t = threadIdx.x;
    if (t == 0) s_total = 0.f;

    for (int img = 0; img < NIMG; ++img) {
        if (t == 0) { s_num = 0.f; s_pull = 0.f; s_push = 0.f; }
        __syncthreads();
        for (int gi = t; gi < NGROUP; gi += 256) {
            float c = counts[img * NSEG + gi + 1];
            float v = (c > 0.f) ? 1.f : 0.f;
            s_valid[gi] = v;
            s_tag[gi * 4 + 0] = means[(img * NSEG + gi + 1) * 4 + 0];
            s_tag[gi * 4 + 1] = means[(img * NSEG + gi + 1) * 4 + 1];
            s_tag[gi * 4 + 2] = means[(img * NSEG + gi + 1) * 4 + 2];
            s_tag[gi * 4 + 3] = means[(img * NSEG + gi + 1) * 4 + 3];
            if (v != 0.f) atomicAdd(&s_num, 1.f);
        }
        __syncthreads();
        const float num = s_num;

        float pp = 0.f;
        for (int gi = t; gi < NGROUP; gi += 256) {
            float c = counts[img * NSEG + gi + 1];
            float gw = wlsum[img * NSEG + gi + 1] / fmaxf(c * 4.f, 1.f);
            pp += gw * s_valid[gi];
        }
        float ps = 0.f;
        for (int idx = t; idx < NGROUP * NGROUP; idx += 256) {
            int a = idx >> 7, b = idx & (NGROUP - 1);
            float dx = s_tag[a * 4 + 0] - s_tag[b * 4 + 0];
            float dy = s_tag[a * 4 + 1] - s_tag[b * 4 + 1];
            float dz = s_tag[a * 4 + 2] - s_tag[b * 4 + 2];
            float dw = s_tag[a * 4 + 3] - s_tag[b * 4 + 3];
            float d2 = dx * dx + dy * dy + dz * dz + dw * dw;
            ps += expf(-d2) * s_valid[a] * s_valid[b];
        }
        atomicAdd(&s_pull, pp);
        atomicAdd(&s_push, ps);
        __syncthreads();
        if (t == 0) {
            float pull = s_pull / (num + 1e-6f);
            float push = (s_push - num) / ((num - 1.f) * num + 1e-6f) * 0.5f;
            s_total += push + pull;
        }
        __syncthreads();
    }
    if (t == 0) out[0] = s_total * (1.f / NIMG);
}

// ---------------------------------------------------------------------------
extern "C" void kernel_launch(void* const* d_in, const int* in_sizes, int n_in,
                              void* d_out, int out_size, void* d_ws, size_t ws_size,
                              hipStream_t stream) {
    const float4* pred = (const float4*)d_in[0];
    const int* gt = (const int*)d_in[1];
    const int n_per_img = in_sizes[1] / NIMG;  // 2,000,000

    float* ws = (float*)d_ws;
    float* counts = ws;                         // NIMG*NSEG           = 516
    float* sums   = ws + 516;                   // NIMG*NSEG*4         = 2064
    float* wlsum  = ws + 516 + 2064;            // NIMG*NSEG           = 516
    float* means  = ws + 516 + 2064 + 516;      // NIMG*NSEG*4         = 2064

    hipMemsetAsync(d_ws, 0, (size_t)(516 + 2064 + 516) * sizeof(float), stream);

    dim3 grid(512, NIMG);   // 2048 blocks = 8/CU for DS-latency hiding
    accum_kernel<<<grid, 256, 0, stream>>>(pred, gt, counts, sums, n_per_img);
    means_kernel<<<3, 256, 0, stream>>>(counts, sums, means);
    wl_kernel<<<grid, 256, 0, stream>>>(pred, gt, means, wlsum, n_per_img);
    final_kernel<<<1, 256, 0, stream>>>(counts, wlsum, means, (float*)d_out);
}

// Round 3
// 279.813 us; speedup vs baseline: 1.5212x; 1.5212x over previous
//
#include <hip/hip_runtime.h>
#include <math.h>

#define NSEG 129
#define NGROUP 128
#define NIMG 4
#define R 4            // LDS histogram replicas (indexed by lane & 3)

// Fixed-point scales for integer LDS accumulation
#define QS 65536.0f         // pred sums: 2^16
#define QS_INV (1.0f / 65536.0f)
#define QW 8192.0f          // wing-loss sums: 2^13
#define QW_INV (1.0f / 8192.0f)

// ALPHA=10, BETA=2 ; C = ALPHA - ALPHA*ln(1+ALPHA/BETA) = 10 - 10*ln(6)
#define WING_C (-7.917594692280550f)

// ---------------------------------------------------------------------------
// Pass 1: per-(img,seg) counts and sums via replicated INT LDS histogram.
// grid = (blocksX, NIMG), block = 256
__global__ __launch_bounds__(256) void accum_kernel(const float4* __restrict__ pred,
                                                    const int* __restrict__ gt,
                                                    float* __restrict__ counts,
                                                    float* __restrict__ sums,
                                                    int n) {
    __shared__ int s_cnt[NSEG * R];
    __shared__ int s_sum[4 * NSEG * R];
    const int img = blockIdx.y;
    for (int i = threadIdx.x; i < NSEG * R; i += 256) s_cnt[i] = 0;
    for (int i = threadIdx.x; i < 4 * NSEG * R; i += 256) s_sum[i] = 0;
    __syncthreads();

    const int r = threadIdx.x & (R - 1);
    const float4* p = pred + (size_t)img * n;
    const int* g = gt + (size_t)img * n;
    for (int i = blockIdx.x * 256 + threadIdx.x; i < n; i += gridDim.x * 256) {
        int seg = g[i] + 1;
        seg = max(0, min(NSEG - 1, seg));
        float4 v = p[i];
        int base = seg * R + r;
        atomicAdd(&s_cnt[base], 1);
        atomicAdd(&s_sum[0 * NSEG * R + base], (int)rintf(v.x * QS));
        atomicAdd(&s_sum[1 * NSEG * R + base], (int)rintf(v.y * QS));
        atomicAdd(&s_sum[2 * NSEG * R + base], (int)rintf(v.z * QS));
        atomicAdd(&s_sum[3 * NSEG * R + base], (int)rintf(v.w * QS));
    }
    __syncthreads();

    for (int i = threadIdx.x; i < NSEG; i += 256) {
        int c = s_cnt[i * R + 0] + s_cnt[i * R + 1] + s_cnt[i * R + 2] + s_cnt[i * R + 3];
        if (c != 0) {
            atomicAdd(&counts[img * NSEG + i], (float)c);
            #pragma unroll
            for (int k = 0; k < 4; ++k) {
                const int* b = &s_sum[k * NSEG * R + i * R];
                int sk = b[0] + b[1] + b[2] + b[3];
                atomicAdd(&sums[(img * NSEG + i) * 4 + k], (float)sk * QS_INV);
            }
        }
    }
}

// ---------------------------------------------------------------------------
// Pass 2: means = sums / max(counts, 1)
__global__ __launch_bounds__(256) void means_kernel(const float* __restrict__ counts,
                                                    const float* __restrict__ sums,
                                                    float* __restrict__ means) {
    int idx = blockIdx.x * 256 + threadIdx.x;  // over NIMG*NSEG
    if (idx < NIMG * NSEG) {
        float c = fmaxf(counts[idx], 1.f);
        means[idx * 4 + 0] = sums[idx * 4 + 0] / c;
        means[idx * 4 + 1] = sums[idx * 4 + 1] / c;
        means[idx * 4 + 2] = sums[idx * 4 + 2] / c;
        means[idx * 4 + 3] = sums[idx * 4 + 3] / c;
    }
}

// ---------------------------------------------------------------------------
// Pass 3: wing loss vs means[seg]; segment-sum via replicated INT LDS histogram.
__global__ __launch_bounds__(256) void wl_kernel(const float4* __restrict__ pred,
                                                 const int* __restrict__ gt,
                                                 const float* __restrict__ means,
                                                 float* __restrict__ wlsum,
                                                 int n) {
    __shared__ float s_mean[NSEG * 5];   // stride 5 (coprime to 32) for gather spread
    __shared__ int s_wl[NSEG * R];
    const int img = blockIdx.y;
    for (int i = threadIdx.x; i < NSEG; i += 256) {
        s_mean[i * 5 + 0] = means[(img * NSEG + i) * 4 + 0];
        s_mean[i * 5 + 1] = means[(img * NSEG + i) * 4 + 1];
        s_mean[i * 5 + 2] = means[(img * NSEG + i) * 4 + 2];
        s_mean[i * 5 + 3] = means[(img * NSEG + i) * 4 + 3];
    }
    for (int i = threadIdx.x; i < NSEG * R; i += 256) s_wl[i] = 0;
    __syncthreads();

    const int r = threadIdx.x & (R - 1);
    const float4* p = pred + (size_t)img * n;
    const int* g = gt + (size_t)img * n;
    for (int i = blockIdx.x * 256 + threadIdx.x; i < n; i += gridDim.x * 256) {
        int seg = g[i] + 1;
        seg = max(0, min(NSEG - 1, seg));
        float4 v = p[i];
        float d0 = fabsf(v.x - s_mean[seg * 5 + 0]);
        float d1 = fabsf(v.y - s_mean[seg * 5 + 1]);
        float d2 = fabsf(v.z - s_mean[seg * 5 + 2]);
        float d3 = fabsf(v.w - s_mean[seg * 5 + 3]);
        float w = 0.f;
        w += (d0 < 10.f) ? 10.f * log1pf(d0 * 0.5f) : (d0 - WING_C);
        w += (d1 < 10.f) ? 10.f * log1pf(d1 * 0.5f) : (d1 - WING_C);
        w += (d2 < 10.f) ? 10.f * log1pf(d2 * 0.5f) : (d2 - WING_C);
        w += (d3 < 10.f) ? 10.f * log1pf(d3 * 0.5f) : (d3 - WING_C);
        atomicAdd(&s_wl[seg * R + r], (int)rintf(w * QW));
    }
    __syncthreads();

    for (int i = threadIdx.x; i < NSEG; i += 256) {
        int w = s_wl[i * R + 0] + s_wl[i * R + 1] + s_wl[i * R + 2] + s_wl[i * R + 3];
        if (w != 0) atomicAdd(&wlsum[img * NSEG + i], (float)w * QW_INV);
    }
}

// ---------------------------------------------------------------------------
// Pass 4: per-image pull + push, averaged. Single block.
__global__ __launch_bounds__(256) void final_kernel(const float* __restrict__ counts,
                                                    const float* __restrict__ wlsum,
                                                    const float* __restrict__ means,
                                                    float* __restrict__ out) {
    __shared__ float s_tag[NGROUP * 4];
    __shared__ float s_valid[NGROUP];
    __shared__ float s_num, s_pull, s_push, s_total;
    const int t = threadIdx.x;
    if (t == 0) s_total = 0.f;

    for (int img = 0; img < NIMG; ++img) {
        if (t == 0) { s_num = 0.f; s_pull = 0.f; s_push = 0.f; }
        __syncthreads();
        for (int gi = t; gi < NGROUP; gi += 256) {
            float c = counts[img * NSEG + gi + 1];
            float v = (c > 0.f) ? 1.f : 0.f;
            s_valid[gi] = v;
            s_tag[gi * 4 + 0] = means[(img * NSEG + gi + 1) * 4 + 0];
            s_tag[gi * 4 + 1] = means[(img * NSEG + gi + 1) * 4 + 1];
            s_tag[gi * 4 + 2] = means[(img * NSEG + gi + 1) * 4 + 2];
            s_tag[gi * 4 + 3] = means[(img * NSEG + gi + 1) * 4 + 3];
            if (v != 0.f) atomicAdd(&s_num, 1.f);
        }
        __syncthreads();
        const float num = s_num;

        float pp = 0.f;
        for (int gi = t; gi < NGROUP; gi += 256) {
            float c = counts[img * NSEG + gi + 1];
            float gw = wlsum[img * NSEG + gi + 1] / fmaxf(c * 4.f, 1.f);
            pp += gw * s_valid[gi];
        }
        float ps = 0.f;
        for (int idx = t; idx < NGROUP * NGROUP; idx += 256) {
            int a = idx >> 7, b = idx & (NGROUP - 1);
            float dx = s_tag[a * 4 + 0] - s_tag[b * 4 + 0];
            float dy = s_tag[a * 4 + 1] - s_tag[b * 4 + 1];
            float dz = s_tag[a * 4 + 2] - s_tag[b * 4 + 2];
            float dw = s_tag[a * 4 + 3] - s_tag[b * 4 + 3];
            float d2 = dx * dx + dy * dy + dz * dz + dw * dw;
            ps += expf(-d2) * s_valid[a] * s_valid[b];
        }
        atomicAdd(&s_pull, pp);
        atomicAdd(&s_push, ps);
        __syncthreads();
        if (t == 0) {
            float pull = s_pull / (num + 1e-6f);
            float push = (s_push - num) / ((num - 1.f) * num + 1e-6f) * 0.5f;
            s_total += push + pull;
        }
        __syncthreads();
    }
    if (t == 0) out[0] = s_total * (1.f / NIMG);
}

// ---------------------------------------------------------------------------
extern "C" void kernel_launch(void* const* d_in, const int* in_sizes, int n_in,
                              void* d_out, int out_size, void* d_ws, size_t ws_size,
                              hipStream_t stream) {
    const float4* pred = (const float4*)d_in[0];
    const int* gt = (const int*)d_in[1];
    const int n_per_img = in_sizes[1] / NIMG;  // 2,000,000

    float* ws = (float*)d_ws;
    float* counts = ws;                         // NIMG*NSEG           = 516
    float* sums   = ws + 516;                   // NIMG*NSEG*4         = 2064
    float* wlsum  = ws + 516 + 2064;            // NIMG*NSEG           = 516
    float* means  = ws + 516 + 2064 + 516;      // NIMG*NSEG*4         = 2064

    hipMemsetAsync(d_ws, 0, (size_t)(516 + 2064 + 516) * sizeof(float), stream);

    dim3 grid(512, NIMG);
    accum_kernel<<<grid, 256, 0, stream>>>(pred, gt, counts, sums, n_per_img);
    means_kernel<<<3, 256, 0, stream>>>(counts, sums, means);
    wl_kernel<<<grid, 256, 0, stream>>>(pred, gt, means, wlsum, n_per_img);
    final_kernel<<<1, 256, 0, stream>>>(counts, wlsum, means, (float*)d_out);
}

// Round 4
// 251.770 us; speedup vs baseline: 1.6907x; 1.1114x over previous
//
#include <hip/hip_runtime.h>
#include <math.h>

#define NSEG 129
#define NGROUP 128
#define NIMG 4
#define R 4            // LDS histogram replicas (indexed by lane & 3)
#define BATCH 8        // elements in flight per wave per loop iteration

// Fixed-point scales
#define QS 65536.0f          // pred sums: 2^16
#define QS_INV (1.0f / 65536.0f)
#define BIAS 524288          // 2^19 per-add bias so packed 32-bit slots stay non-negative
#define QW 8192.0f           // wing-loss sums: 2^13
#define QW_INV (1.0f / 8192.0f)

// ALPHA=10, BETA=2 ; C = ALPHA - ALPHA*ln(1+ALPHA/BETA) = 10 - 10*ln(6)
#define WING_C (-7.917594692280550f)
#define WING_SCALE 6.93147180559945f   // 10*ln(2): 10*log1p(x) == WING_SCALE*log2(1+x)

// ---------------------------------------------------------------------------
// Pass 1: counts + packed quantized sums via replicated INT LDS histogram.
// grid = (blocksX, NIMG), block = 256
__global__ __launch_bounds__(256) void accum_kernel(const float4* __restrict__ pred,
                                                    const int* __restrict__ gt,
                                                    float* __restrict__ counts,
                                                    float* __restrict__ sums,
                                                    int n) {
    __shared__ unsigned int s_cnt[NSEG * R];
    __shared__ unsigned long long s_xy[NSEG * R];
    __shared__ unsigned long long s_zw[NSEG * R];
    const int img = blockIdx.y;
    for (int i = threadIdx.x; i < NSEG * R; i += 256) { s_cnt[i] = 0u; s_xy[i] = 0ull; s_zw[i] = 0ull; }
    __syncthreads();

    const int r = threadIdx.x & (R - 1);
    const float4* p = pred + (size_t)img * n;
    const int* g = gt + (size_t)img * n;
    const int stride = gridDim.x * 256;
    const int tid0 = blockIdx.x * 256 + threadIdx.x;

    for (int base = tid0; base < n; base += stride * BATCH) {
        float4 v[BATCH];
        int sg[BATCH];
        #pragma unroll
        for (int j = 0; j < BATCH; ++j) {
            int i = base + j * stride;
            if (i < n) { sg[j] = g[i]; v[j] = p[i]; } else { sg[j] = -1000; }
        }
        #pragma unroll
        for (int j = 0; j < BATCH; ++j) {
            if (sg[j] > -1000) {
                int s = max(0, min(NSEG - 1, sg[j] + 1));
                int slot = s * R + r;
                atomicAdd(&s_cnt[slot], 1u);
                unsigned int xq = (unsigned int)(__float2int_rn(v[j].x * QS) + BIAS);
                unsigned int yq = (unsigned int)(__float2int_rn(v[j].y * QS) + BIAS);
                unsigned int zq = (unsigned int)(__float2int_rn(v[j].z * QS) + BIAS);
                unsigned int wq = (unsigned int)(__float2int_rn(v[j].w * QS) + BIAS);
                atomicAdd(&s_xy[slot], (unsigned long long)xq | ((unsigned long long)yq << 32));
                atomicAdd(&s_zw[slot], (unsigned long long)zq | ((unsigned long long)wq << 32));
            }
        }
    }
    __syncthreads();

    for (int i = threadIdx.x; i < NSEG; i += 256) {
        unsigned int c = 0;
        long long cx = 0, cy = 0, cz = 0, cw = 0;
        #pragma unroll
        for (int rr = 0; rr < R; ++rr) {
            int slot = i * R + rr;
            unsigned int cc = s_cnt[slot];
            c += cc;
            unsigned long long xy = s_xy[slot], zw = s_zw[slot];
            long long b = (long long)cc * (long long)BIAS;
            cx += (long long)(xy & 0xffffffffull) - b;
            cy += (long long)(xy >> 32) - b;
            cz += (long long)(zw & 0xffffffffull) - b;
            cw += (long long)(zw >> 32) - b;
        }
        if (c) {
            atomicAdd(&counts[img * NSEG + i], (float)c);
            atomicAdd(&sums[(img * NSEG + i) * 4 + 0], (float)cx * QS_INV);
            atomicAdd(&sums[(img * NSEG + i) * 4 + 1], (float)cy * QS_INV);
            atomicAdd(&sums[(img * NSEG + i) * 4 + 2], (float)cz * QS_INV);
            atomicAdd(&sums[(img * NSEG + i) * 4 + 3], (float)cw * QS_INV);
        }
    }
}

// ---------------------------------------------------------------------------
// Pass 2: means = sums / max(counts, 1)
__global__ __launch_bounds__(256) void means_kernel(const float* __restrict__ counts,
                                                    const float* __restrict__ sums,
                                                    float* __restrict__ means) {
    int idx = blockIdx.x * 256 + threadIdx.x;  // over NIMG*NSEG
    if (idx < NIMG * NSEG) {
        float c = fmaxf(counts[idx], 1.f);
        means[idx * 4 + 0] = sums[idx * 4 + 0] / c;
        means[idx * 4 + 1] = sums[idx * 4 + 1] / c;
        means[idx * 4 + 2] = sums[idx * 4 + 2] / c;
        means[idx * 4 + 3] = sums[idx * 4 + 3] / c;
    }
}

// ---------------------------------------------------------------------------
// Pass 3: wing loss vs means[seg]; segment-sum via replicated INT LDS histogram.
__global__ __launch_bounds__(256) void wl_kernel(const float4* __restrict__ pred,
                                                 const int* __restrict__ gt,
                                                 const float4* __restrict__ means,
                                                 float* __restrict__ wlsum,
                                                 int n) {
    __shared__ float4 s_mean[NSEG];
    __shared__ int s_wl[NSEG * R];
    const int img = blockIdx.y;
    for (int i = threadIdx.x; i < NSEG; i += 256) s_mean[i] = means[img * NSEG + i];
    for (int i = threadIdx.x; i < NSEG * R; i += 256) s_wl[i] = 0;
    __syncthreads();

    const int r = threadIdx.x & (R - 1);
    const float4* p = pred + (size_t)img * n;
    const int* g = gt + (size_t)img * n;
    const int stride = gridDim.x * 256;
    const int tid0 = blockIdx.x * 256 + threadIdx.x;

    for (int base = tid0; base < n; base += stride * BATCH) {
        float4 v[BATCH];
        int sg[BATCH];
        #pragma unroll
        for (int j = 0; j < BATCH; ++j) {
            int i = base + j * stride;
            if (i < n) { sg[j] = g[i]; v[j] = p[i]; } else { sg[j] = -1000; }
        }
        #pragma unroll
        for (int j = 0; j < BATCH; ++j) {
            if (sg[j] > -1000) {
                int s = max(0, min(NSEG - 1, sg[j] + 1));
                float4 m = s_mean[s];
                float d0 = fabsf(v[j].x - m.x);
                float d1 = fabsf(v[j].y - m.y);
                float d2 = fabsf(v[j].z - m.z);
                float d3 = fabsf(v[j].w - m.w);
                float w = 0.f;
                w += (d0 < 10.f) ? WING_SCALE * __log2f(fmaf(0.5f, d0, 1.0f)) : (d0 - WING_C);
                w += (d1 < 10.f) ? WING_SCALE * __log2f(fmaf(0.5f, d1, 1.0f)) : (d1 - WING_C);
                w += (d2 < 10.f) ? WING_SCALE * __log2f(fmaf(0.5f, d2, 1.0f)) : (d2 - WING_C);
                w += (d3 < 10.f) ? WING_SCALE * __log2f(fmaf(0.5f, d3, 1.0f)) : (d3 - WING_C);
                atomicAdd(&s_wl[s * R + r], __float2int_rn(w * QW));
            }
        }
    }
    __syncthreads();

    for (int i = threadIdx.x; i < NSEG; i += 256) {
        int w = s_wl[i * R + 0] + s_wl[i * R + 1] + s_wl[i * R + 2] + s_wl[i * R + 3];
        if (w != 0) atomicAdd(&wlsum[img * NSEG + i], (float)w * QW_INV);
    }
}

// ---------------------------------------------------------------------------
// Pass 4: per-image pull + push, averaged. Single block.
__global__ __launch_bounds__(256) void final_kernel(const float* __restrict__ counts,
                                                    const float* __restrict__ wlsum,
                                                    const float* __restrict__ means,
                                                    float* __restrict__ out) {
    __shared__ float s_tag[NGROUP * 4];
    __shared__ float s_valid[NGROUP];
    __shared__ float s_num, s_pull, s_push, s_total;
    const int t = threadIdx.x;
    if (t == 0) s_total = 0.f;

    for (int img = 0; img < NIMG; ++img) {
        if (t == 0) { s_num = 0.f; s_pull = 0.f; s_push = 0.f; }
        __syncthreads();
        for (int gi = t; gi < NGROUP; gi += 256) {
            float c = counts[img * NSEG + gi + 1];
            float v = (c > 0.f) ? 1.f : 0.f;
            s_valid[gi] = v;
            s_tag[gi * 4 + 0] = means[(img * NSEG + gi + 1) * 4 + 0];
            s_tag[gi * 4 + 1] = means[(img * NSEG + gi + 1) * 4 + 1];
            s_tag[gi * 4 + 2] = means[(img * NSEG + gi + 1) * 4 + 2];
            s_tag[gi * 4 + 3] = means[(img * NSEG + gi + 1) * 4 + 3];
            if (v != 0.f) atomicAdd(&s_num, 1.f);
        }
        __syncthreads();
        const float num = s_num;

        float pp = 0.f;
        for (int gi = t; gi < NGROUP; gi += 256) {
            float c = counts[img * NSEG + gi + 1];
            float gw = wlsum[img * NSEG + gi + 1] / fmaxf(c * 4.f, 1.f);
            pp += gw * s_valid[gi];
        }
        float ps = 0.f;
        for (int idx = t; idx < NGROUP * NGROUP; idx += 256) {
            int a = idx >> 7, b = idx & (NGROUP - 1);
            float dx = s_tag[a * 4 + 0] - s_tag[b * 4 + 0];
            float dy = s_tag[a * 4 + 1] - s_tag[b * 4 + 1];
            float dz = s_tag[a * 4 + 2] - s_tag[b * 4 + 2];
            float dw = s_tag[a * 4 + 3] - s_tag[b * 4 + 3];
            float d2 = dx * dx + dy * dy + dz * dz + dw * dw;
            ps += expf(-d2) * s_valid[a] * s_valid[b];
        }
        atomicAdd(&s_pull, pp);
        atomicAdd(&s_push, ps);
        __syncthreads();
        if (t == 0) {
            float pull = s_pull / (num + 1e-6f);
            float push = (s_push - num) / ((num - 1.f) * num + 1e-6f) * 0.5f;
            s_total += push + pull;
        }
        __syncthreads();
    }
    if (t == 0) out[0] = s_total * (1.f / NIMG);
}

// ---------------------------------------------------------------------------
extern "C" void kernel_launch(void* const* d_in, const int* in_sizes, int n_in,
                              void* d_out, int out_size, void* d_ws, size_t ws_size,
                              hipStream_t stream) {
    const float4* pred = (const float4*)d_in[0];
    const int* gt = (const int*)d_in[1];
    const int n_per_img = in_sizes[1] / NIMG;  // 2,000,000

    float* ws = (float*)d_ws;
    float* counts = ws;                         // NIMG*NSEG           = 516
    float* sums   = ws + 516;                   // NIMG*NSEG*4         = 2064
    float* wlsum  = ws + 516 + 2064;            // NIMG*NSEG           = 516
    float* means  = ws + 516 + 2064 + 516;      // NIMG*NSEG*4         = 2064

    hipMemsetAsync(d_ws, 0, (size_t)(516 + 2064 + 516) * sizeof(float), stream);

    dim3 grid(512, NIMG);
    accum_kernel<<<grid, 256, 0, stream>>>(pred, gt, counts, sums, n_per_img);
    means_kernel<<<3, 256, 0, stream>>>(counts, sums, means);
    wl_kernel<<<grid, 256, 0, stream>>>(pred, gt, (const float4*)means, wlsum, n_per_img);
    final_kernel<<<1, 256, 0, stream>>>(counts, wlsum, means, (float*)d_out);
}